// Round 1
// baseline (273.240 us; speedup 1.0000x reference)
//
#include <hip/hip_runtime.h>
#include <hip/hip_fp16.h>
#include <math.h>

#define LRELU_ALPHA 0.2f
#define NEG_INF -1000000000.0f

constexpr int B_ = 8, N_ = 2048, FIN = 128, FOUT = 64;

typedef _Float16 __attribute__((ext_vector_type(8))) f16x8;
typedef float __attribute__((ext_vector_type(4))) f32x4;

// ---------------------------------------------------------------------------
// Kernel 1 (unchanged, proven): Wh = h @ W^T (fp32), emitted as fp16
// transposed WhT[b][o][n]; also s1 = Wh@a1, s2 = Wh@a2 (fp32).
// ---------------------------------------------------------------------------
__global__ __launch_bounds__(256) void k_wh(
    const float* __restrict__ h, const float* __restrict__ W,
    const float* __restrict__ a, unsigned short* __restrict__ WhT,
    float* __restrict__ s1, float* __restrict__ s2) {
  __shared__ float Wt[128][65];  // [f][o]: read bank (f+o)%32 -> conflict-free
  __shared__ float hs[16][128];

  const int t = threadIdx.x;
  const int row0 = blockIdx.x * 16;

  for (int e = t; e < 64 * 128; e += 256) {
    int o = e >> 7, f = e & 127;
    Wt[f][o] = W[e];
  }
  {
    const float4* hg = (const float4*)(h + (size_t)row0 * FIN);
    for (int i4 = t; i4 < 16 * 32; i4 += 256) {
      int r = i4 >> 5, f4 = i4 & 31;
      *(float4*)&hs[r][f4 * 4] = hg[i4];
    }
  }
  __syncthreads();

  const int wave = t >> 6, lane = t & 63;  // lane = o
  float acc[4] = {0.f, 0.f, 0.f, 0.f};
#pragma unroll 4
  for (int f4 = 0; f4 < 32; ++f4) {
    float w0 = Wt[4 * f4 + 0][lane], w1 = Wt[4 * f4 + 1][lane];
    float w2 = Wt[4 * f4 + 2][lane], w3 = Wt[4 * f4 + 3][lane];
#pragma unroll
    for (int r = 0; r < 4; ++r) {
      float4 hv = *(const float4*)&hs[wave * 4 + r][f4 * 4];
      acc[r] += hv.x * w0 + hv.y * w1 + hv.z * w2 + hv.w * w3;
    }
  }

  const float a1v = a[lane], a2v = a[64 + lane];
  const int b = row0 / N_;
#pragma unroll
  for (int r = 0; r < 4; ++r) {
    const int row = row0 + wave * 4 + r;
    const int n = row - b * N_;
    const float v = acc[r];
    WhT[((size_t)b * 64 + lane) * N_ + n] = __half_as_ushort(__float2half(v));
    float p1 = v * a1v, p2 = v * a2v;
#pragma unroll
    for (int d = 32; d; d >>= 1) {
      p1 += __shfl_xor(p1, d, 64);
      p2 += __shfl_xor(p2, d, 64);
    }
    if (lane == 0) { s1[row] = p1; s2[row] = p2; }
  }
}

// ---------------------------------------------------------------------------
// Kernel 2 v2: masked softmax + att@Wh, BARRIER-FREE register pipeline.
// Block = 32 i-rows x 64 o, 4 waves: wave = (rg = wave&1) x (o-pair p0).
// No LDS staging: each lane's adj needs (16 consecutive j = int4 pair) and
// B-fragment needs (8 consecutive fp16 = 16B) are loaded straight to VGPRs
// in the exact MFMA fragment layout. 4 named register slots = 4 chunks in
// flight (~900 cy cover). Row sums come from an extra MFMA vs a ones-vector:
// accS[r] = rowsum(q*4+r), already indexed like the C/D write layout.
// p = exp(lrelu(s1+s2) - 2): shift folded into per-lane consts c1/c2.
// ---------------------------------------------------------------------------
__global__ __launch_bounds__(256, 2) void k_attn(
    const unsigned short* __restrict__ WhT,
    const float* __restrict__ s1g, const float* __restrict__ s2g,
    const int* __restrict__ adj, float* __restrict__ out) {
  __shared__ float s2s[N_];

  const int t = threadIdx.x;
  const int wave = t >> 6, lane = t & 63;
  const int m = lane & 15, q = lane >> 4;
  const int b = blockIdx.y;
  const int i0 = blockIdx.x * 32;
  const int rg = wave & 1;         // row-group (rows rg*16..+16)
  const int p0 = (wave >> 1) * 2;  // first o-group of this wave's pair

  // preload s2 row-block (8 KB) -- the only LDS use
  {
    const float4* s2R = (const float4*)(s2g + (size_t)b * N_);
    for (int i = t; i < N_ / 4; i += 256) ((float4*)s2s)[i] = s2R[i];
  }

  const int row_i = i0 + rg * 16 + m;
  const int* adjR = adj + (size_t)b * N_ * N_ + (size_t)row_i * N_;
  const unsigned short* whB = WhT + (size_t)b * 64 * N_;
  const unsigned short* bp0 = whB + (size_t)((p0 + 0) * 16 + m) * N_ + q * 8;
  const unsigned short* bp1 = whB + (size_t)((p0 + 1) * 16 + m) * N_ + q * 8;

  const float s1r = s1g[b * N_ + row_i];
  const float c1 = s1r - 2.0f;                // x - 2 branch
  const float c2 = LRELU_ALPHA * s1r - 2.0f;  // 0.2x - 2 branch

  f16x8 ones;
#pragma unroll
  for (int j = 0; j < 8; ++j) ones[j] = (_Float16)1.0f;

  __syncthreads();  // s2s visible; the only barrier in the kernel

  f32x4 acc0 = {0.f, 0.f, 0.f, 0.f}, acc1 = acc0, accS = acc0;

// 64 j per chunk: adj = 4x int4 (ks=0: +0,+4 ; ks=1: +32,+36 ints),
// B-frags = 2 o-groups x 2 ks, 16B each, in MFMA B layout.
#define DECL_SLOT(P) int4 P##a0, P##a1, P##a2, P##a3; \
                     f16x8 P##b0, P##b1, P##b2, P##b3;
#define LOAD(P, c) {                                                     \
    const int* ap = adjR + (c) * 64 + q * 8;                             \
    P##a0 = *(const int4*)ap;                                            \
    P##a1 = *(const int4*)(ap + 4);                                      \
    P##a2 = *(const int4*)(ap + 32);                                     \
    P##a3 = *(const int4*)(ap + 36);                                     \
    P##b0 = *(const f16x8*)(bp0 + (c) * 64);                             \
    P##b1 = *(const f16x8*)(bp0 + (c) * 64 + 32);                        \
    P##b2 = *(const f16x8*)(bp1 + (c) * 64);                             \
    P##b3 = *(const f16x8*)(bp1 + (c) * 64 + 32);                        \
  }
#define ELEM8(af, AV0, AV1, SA, SB) {                                    \
    int av[8] = {AV0.x, AV0.y, AV0.z, AV0.w, AV1.x, AV1.y, AV1.z, AV1.w};\
    float xs[8] = {SA.x, SA.y, SA.z, SA.w, SB.x, SB.y, SB.z, SB.w};      \
    _Pragma("unroll") for (int j = 0; j < 8; ++j) {                      \
      float e = fmaxf(c1 + xs[j], fmaf(LRELU_ALPHA, xs[j], c2));         \
      e = av[j] ? e : NEG_INF;                                           \
      af[j] = (_Float16)__expf(e);  /* masked -> exactly 0.0 */          \
    }                                                                    \
  }
#define CONSUME(P, c) {                                                  \
    const float* sp = s2s + (c) * 64 + q * 8;                            \
    float4 s0a = *(const float4*)sp;                                     \
    float4 s0b = *(const float4*)(sp + 4);                               \
    float4 s1a = *(const float4*)(sp + 32);                              \
    float4 s1b = *(const float4*)(sp + 36);                              \
    f16x8 af0, af1;                                                      \
    ELEM8(af0, P##a0, P##a1, s0a, s0b);                                  \
    ELEM8(af1, P##a2, P##a3, s1a, s1b);                                  \
    acc0 = __builtin_amdgcn_mfma_f32_16x16x32_f16(af0, P##b0, acc0, 0, 0, 0); \
    acc1 = __builtin_amdgcn_mfma_f32_16x16x32_f16(af0, P##b2, acc1, 0, 0, 0); \
    accS = __builtin_amdgcn_mfma_f32_16x16x32_f16(af0, ones, accS, 0, 0, 0);  \
    acc0 = __builtin_amdgcn_mfma_f32_16x16x32_f16(af1, P##b1, acc0, 0, 0, 0); \
    acc1 = __builtin_amdgcn_mfma_f32_16x16x32_f16(af1, P##b3, acc1, 0, 0, 0); \
    accS = __builtin_amdgcn_mfma_f32_16x16x32_f16(af1, ones, accS, 0, 0, 0);  \
  }

  DECL_SLOT(u) DECL_SLOT(v) DECL_SLOT(w) DECL_SLOT(x)
  LOAD(u, 0) LOAD(v, 1) LOAD(w, 2) LOAD(x, 3)

  for (int cc = 0; cc < 8; ++cc) {
    const int c = 4 * cc;
    const int cn = (cc < 7) ? c + 4 : c;  // last iter: harmless L2-hot reload
    CONSUME(u, c + 0) LOAD(u, cn + 0)
    CONSUME(v, c + 1) LOAD(v, cn + 1)
    CONSUME(w, c + 2) LOAD(w, cn + 2)
    CONSUME(x, c + 3) LOAD(x, cn + 3)
  }

  // C/D layout: row_in_tile = q*4 + r, col = m; accS[r] = rowsum(q*4+r)
#pragma unroll
  for (int r = 0; r < 4; ++r) {
    const int ri = q * 4 + r;
    const float l = accS[r];
    const float inv = (l == 0.f) ? 1.f : 1.f / l;  // fully-masked row guard
    const size_t row = (size_t)b * N_ + i0 + rg * 16 + ri;
    out[row * FOUT + (p0 + 0) * 16 + m] = acc0[r] * inv;
    out[row * FOUT + (p0 + 1) * 16 + m] = acc1[r] * inv;
  }
#undef DECL_SLOT
#undef LOAD
#undef ELEM8
#undef CONSUME
}

extern "C" void kernel_launch(void* const* d_in, const int* in_sizes, int n_in,
                              void* d_out, int out_size, void* d_ws, size_t ws_size,
                              hipStream_t stream) {
  const float* h   = (const float*)d_in[0];
  const int*   adj = (const int*)d_in[1];
  const float* W   = (const float*)d_in[2];
  const float* a   = (const float*)d_in[3];
  float* out = (float*)d_out;

  // ws: WhT fp16 (2 MB) | s1 (64 KB) | s2 (64 KB)
  unsigned short* WhT = (unsigned short*)d_ws;
  float* s1 = (float*)(WhT + (size_t)B_ * 64 * N_);
  float* s2 = s1 + (size_t)B_ * N_;

  k_wh<<<dim3(B_ * N_ / 16), 256, 0, stream>>>(h, W, a, WhT, s1, s2);
  k_attn<<<dim3(N_ / 32, B_), 256, 0, stream>>>(WhT, s1, s2, adj, out);
}

// Round 3
// 222.548 us; speedup vs baseline: 1.2278x; 1.2278x over previous
//
#include <hip/hip_runtime.h>
#include <hip/hip_fp16.h>
#include <math.h>

#define LRELU_ALPHA 0.2f
#define NEG_INF -1000000000.0f
#define L2E 1.44269504088896340736f  // log2(e)

constexpr int B_ = 8, N_ = 2048, FIN = 128, FOUT = 64;

typedef _Float16 __attribute__((ext_vector_type(8))) f16x8;
typedef float __attribute__((ext_vector_type(4))) f32x4;

// async global->LDS, 16B per lane; lane l's data lands at ldsbase + l*16
__device__ __forceinline__ void gload16(const void* g, void* l) {
  __builtin_amdgcn_global_load_lds(
      (const __attribute__((address_space(1))) void*)g,
      (__attribute__((address_space(3))) void*)l, 16, 0, 0);
}

// ---------------------------------------------------------------------------
// Kernel 1 (unchanged, proven): Wh = h @ W^T (fp32), emitted as fp16
// transposed WhT[b][o][n]; also s1 = Wh@a1, s2 = Wh@a2 (fp32).
// ---------------------------------------------------------------------------
__global__ __launch_bounds__(256) void k_wh(
    const float* __restrict__ h, const float* __restrict__ W,
    const float* __restrict__ a, unsigned short* __restrict__ WhT,
    float* __restrict__ s1, float* __restrict__ s2) {
  __shared__ float Wt[128][65];  // [f][o]: read bank (f+o)%32 -> conflict-free
  __shared__ float hs[16][128];

  const int t = threadIdx.x;
  const int row0 = blockIdx.x * 16;

  for (int e = t; e < 64 * 128; e += 256) {
    int o = e >> 7, f = e & 127;
    Wt[f][o] = W[e];
  }
  {
    const float4* hg = (const float4*)(h + (size_t)row0 * FIN);
    for (int i4 = t; i4 < 16 * 32; i4 += 256) {
      int r = i4 >> 5, f4 = i4 & 31;
      *(float4*)&hs[r][f4 * 4] = hg[i4];
    }
  }
  __syncthreads();

  const int wave = t >> 6, lane = t & 63;  // lane = o
  float acc[4] = {0.f, 0.f, 0.f, 0.f};
#pragma unroll 4
  for (int f4 = 0; f4 < 32; ++f4) {
    float w0 = Wt[4 * f4 + 0][lane], w1 = Wt[4 * f4 + 1][lane];
    float w2 = Wt[4 * f4 + 2][lane], w3 = Wt[4 * f4 + 3][lane];
#pragma unroll
    for (int r = 0; r < 4; ++r) {
      float4 hv = *(const float4*)&hs[wave * 4 + r][f4 * 4];
      acc[r] += hv.x * w0 + hv.y * w1 + hv.z * w2 + hv.w * w3;
    }
  }

  const float a1v = a[lane], a2v = a[64 + lane];
  const int b = row0 / N_;
#pragma unroll
  for (int r = 0; r < 4; ++r) {
    const int row = row0 + wave * 4 + r;
    const int n = row - b * N_;
    const float v = acc[r];
    WhT[((size_t)b * 64 + lane) * N_ + n] = __half_as_ushort(__float2half(v));
    float p1 = v * a1v, p2 = v * a2v;
#pragma unroll
    for (int d = 32; d; d >>= 1) {
      p1 += __shfl_xor(p1, d, 64);
      p2 += __shfl_xor(p2, d, 64);
    }
    if (lane == 0) { s1[row] = p1; s2[row] = p2; }
  }
}

// ---------------------------------------------------------------------------
// Kernel 2 v3b: masked softmax + att@Wh, 4-deep DMA pipeline, counted vmcnt.
// Block = 32 i-rows x 64 o; chunks of 64 j. Per chunk 16 KB staged by 16
// global_load_lds_dwordx4 (adj[32][64] int + WhT[64][64] fp16), 4 per wave.
// 4 LDS buffers; stage 3 chunks ahead. Each barrier is preceded by
// s_waitcnt vmcnt(8): each wave waits only its own oldest 4 DMAs (chunk c),
// leaving chunks c+1,c+2 in flight ACROSS the barrier (T3+T4 — never drain
// vmcnt(0) in the main loop). Barrier transitively guarantees other waves'
// chunk-c DMAs landed. Buffer safety: consume(c) precedes STAGE(c+3)
// [which overwrites buf (c-1)&3], and barrier-c separates all consume(c-1)
// from any STAGE(c+3).
// OOB fix vs v3: main loop ends at c=28 so the last STAGE is chunk 31
// (chunk 32 read past the end of adj -> page fault). Epilogue peels
// c=29 (vmcnt(8)), c=30 (vmcnt(4)), c=31 (vmcnt(0)).
// Row sums via MFMA against a ones vector: accS[r] indexed like C/D layout.
// exp in base 2: s2s pre-scaled by log2(e); c1=(s1-2)*L2E, c2=(0.2*s1-2)*L2E
// -> p = exp2(max(c1+x, 0.2x+c2)) == exp(lrelu(s1+s2)-2), one trans op/elem.
// ---------------------------------------------------------------------------
__global__ __launch_bounds__(256, 2) void k_attn(
    const unsigned short* __restrict__ WhT,
    const float* __restrict__ s1g, const float* __restrict__ s2g,
    const int* __restrict__ adj, float* __restrict__ out) {
  __shared__ __align__(16) unsigned char sbuf[4][16 * 1024];
  __shared__ float s2s[N_];

  const int t = threadIdx.x;
  const int wave = t >> 6, lane = t & 63;
  const int m = lane & 15, q = lane >> 4;
  const int b = blockIdx.y;
  const int i0 = blockIdx.x * 32;
  const int rg = wave & 1;         // row-group (rows rg*16..+16)
  const int p0 = (wave >> 1) * 2;  // first o-group of this wave's pair

  const int* adjB = adj + (size_t)b * N_ * N_;
  const unsigned short* whB = WhT + (size_t)b * 64 * N_;

  // preload s2 row-block (8 KB), pre-scaled by log2(e)
  {
    const float4* s2R = (const float4*)(s2g + (size_t)b * N_);
    for (int i = t; i < N_ / 4; i += 256) {
      float4 v = s2R[i];
      v.x *= L2E; v.y *= L2E; v.z *= L2E; v.w *= L2E;
      ((float4*)s2s)[i] = v;
    }
  }

  const float s1r = s1g[b * N_ + i0 + rg * 16 + m];
  const float c1 = (s1r - 2.0f) * L2E;                // x-2 branch (base-2)
  const float c2 = (LRELU_ALPHA * s1r - 2.0f) * L2E;  // 0.2x-2 branch

  f16x8 ones;
#pragma unroll
  for (int j = 0; j < 8; ++j) ones[j] = (_Float16)1.0f;

  // per-wave staging sources (4 DMA instrs per wave per chunk):
  //  waves 0,1: adj rows rg*16..+16, instr ii -> (ks=ii>>1, h=ii&1)
  //  waves 2,3: WhT,               instr ii -> (g=(w-2)*2+(ii>>1), ks=ii&1)
  // LDS slot layout: instr idx*1024 + lane*16, where
  //  adj idx = rg*4 + ks*2 + h ; WhT idx = 8 + g*2 + ks
  const unsigned char* gp[4];
  int gstr;
  if (wave < 2) {
    const size_t r = (size_t)(i0 + wave * 16 + m);
#pragma unroll
    for (int ii = 0; ii < 4; ++ii) {
      int ks = ii >> 1, hh = ii & 1;
      gp[ii] = (const unsigned char*)(adjB + r * N_ + ks * 32 + q * 8 + hh * 4);
    }
    gstr = 64 * 4;   // 64 ints per chunk
  } else {
#pragma unroll
    for (int ii = 0; ii < 4; ++ii) {
      int g = (wave - 2) * 2 + (ii >> 1), ks = ii & 1;
      gp[ii] = (const unsigned char*)(whB + (size_t)(g * 16 + m) * N_ +
                                      ks * 32 + q * 8);
    }
    gstr = 64 * 2;   // 64 fp16 per chunk
  }

#define STAGE(S, c)                                                       \
  {                                                                       \
    _Pragma("unroll") for (int ii = 0; ii < 4; ++ii)                      \
        gload16(gp[ii] + (size_t)(c) * gstr, (S) + (wave * 4 + ii) * 1024); \
  }

  f32x4 acc0 = {0.f, 0.f, 0.f, 0.f}, acc1 = acc0, accS = acc0;

  auto consume = [&](const unsigned char* base, int c) {
#pragma unroll
    for (int ks = 0; ks < 2; ++ks) {
      int4 A0 = *(const int4*)(base + (rg * 4 + ks * 2 + 0) * 1024 + lane * 16);
      int4 A1 = *(const int4*)(base + (rg * 4 + ks * 2 + 1) * 1024 + lane * 16);
      const float* sp = &s2s[c * 64 + ks * 32 + q * 8];
      float4 sv0 = *(const float4*)sp;
      float4 sv1 = *(const float4*)(sp + 4);
      float xs[8] = {sv0.x, sv0.y, sv0.z, sv0.w, sv1.x, sv1.y, sv1.z, sv1.w};
      int avs[8] = {A0.x, A0.y, A0.z, A0.w, A1.x, A1.y, A1.z, A1.w};
      f16x8 af;
#pragma unroll
      for (int j = 0; j < 8; ++j) {
        float x = xs[j];
        float e = fmaxf(c1 + x, fmaf(LRELU_ALPHA, x, c2));
        e = avs[j] ? e : NEG_INF;
        af[j] = (_Float16)__builtin_amdgcn_exp2f(e);  // masked -> exactly 0
      }
      f16x8 b0 = *(const f16x8*)(base + (8 + (p0 + 0) * 2 + ks) * 1024 + lane * 16);
      f16x8 b1 = *(const f16x8*)(base + (8 + (p0 + 1) * 2 + ks) * 1024 + lane * 16);
      acc0 = __builtin_amdgcn_mfma_f32_16x16x32_f16(af, b0, acc0, 0, 0, 0);
      acc1 = __builtin_amdgcn_mfma_f32_16x16x32_f16(af, b1, acc1, 0, 0, 0);
      accS = __builtin_amdgcn_mfma_f32_16x16x32_f16(af, ones, accS, 0, 0, 0);
    }
  };

  // prologue: 3 chunks staged; full drain once (also publishes s2s)
  STAGE(sbuf[0], 0)
  STAGE(sbuf[1], 1)
  STAGE(sbuf[2], 2)
  __syncthreads();

  consume(sbuf[0], 0);
  STAGE(sbuf[3], 3)

  for (int c = 1; c <= 28; ++c) {
    asm volatile("s_waitcnt vmcnt(8)" ::: "memory");  // chunk c landed (own 4)
    __builtin_amdgcn_s_barrier();                     // => all waves' chunk c
    consume(sbuf[c & 3], c);
    STAGE(sbuf[(c + 3) & 3], c + 3)   // last STAGE: chunk 31 at c=28
  }
  // epilogue: chunks 29 (30,31 in flight), 30 (31 in flight), 31
  asm volatile("s_waitcnt vmcnt(8)" ::: "memory");
  __builtin_amdgcn_s_barrier();
  consume(sbuf[1], 29);
  asm volatile("s_waitcnt vmcnt(4)" ::: "memory");
  __builtin_amdgcn_s_barrier();
  consume(sbuf[2], 30);
  asm volatile("s_waitcnt vmcnt(0)" ::: "memory");
  __builtin_amdgcn_s_barrier();
  consume(sbuf[3], 31);

  // C/D layout: row_in_tile = q*4 + r, col = m; accS[r] = rowsum(q*4+r)
#pragma unroll
  for (int r = 0; r < 4; ++r) {
    const int ri = q * 4 + r;
    const float l = accS[r];
    const float inv = (l == 0.f) ? 1.f : 1.f / l;  // fully-masked row guard
    const size_t row = (size_t)b * N_ + i0 + rg * 16 + ri;
    out[row * FOUT + (p0 + 0) * 16 + m] = acc0[r] * inv;
    out[row * FOUT + (p0 + 1) * 16 + m] = acc1[r] * inv;
  }
#undef STAGE
}

extern "C" void kernel_launch(void* const* d_in, const int* in_sizes, int n_in,
                              void* d_out, int out_size, void* d_ws, size_t ws_size,
                              hipStream_t stream) {
  const float* h   = (const float*)d_in[0];
  const int*   adj = (const int*)d_in[1];
  const float* W   = (const float*)d_in[2];
  const float* a   = (const float*)d_in[3];
  float* out = (float*)d_out;

  // ws: WhT fp16 (2 MB) | s1 (64 KB) | s2 (64 KB)
  unsigned short* WhT = (unsigned short*)d_ws;
  float* s1 = (float*)(WhT + (size_t)B_ * 64 * N_);
  float* s2 = s1 + (size_t)B_ * N_;

  k_wh<<<dim3(B_ * N_ / 16), 256, 0, stream>>>(h, W, a, WhT, s1, s2);
  k_attn<<<dim3(N_ / 32, B_), 256, 0, stream>>>(WhT, s1, s2, adj, out);
}